// Round 11
// baseline (1535.570 us; speedup 1.0000x reference)
//
#include <hip/hip_runtime.h>
#include <cmath>

#define B_  128
#define T_  512
#define E_  128
#define H_  128
#define G4  512   // 4*H
#define K_  9

// ---------------------------------------------------------------------------
// Kernel 0a: gather + transpose embeddings once per launch.
//   Xt[k][b*T+t] = embed[sent[b][t]][k]   (33.6 MB, fp32 exact)
// ---------------------------------------------------------------------------
__global__ __launch_bounds__(256)
void gather_x(const int* __restrict__ sent, const float* __restrict__ embed,
              float* __restrict__ Xt)
{
  const int m = blockIdx.x * 256 + threadIdx.x;   // 0 .. B*T-1  (b*T+t)
  const int vid = sent[m];
  const float* er = embed + (size_t)vid * E_;
  const size_t MT = (size_t)B_ * T_;
#pragma unroll
  for (int q = 0; q < 32; ++q) {
    float4 v = *(const float4*)(er + q * 4);      // gather read (once)
    Xt[(size_t)(q * 4 + 0) * MT + m] = v.x;       // coalesced writes
    Xt[(size_t)(q * 4 + 1) * MT + m] = v.y;
    Xt[(size_t)(q * 4 + 2) * MT + m] = v.z;
    Xt[(size_t)(q * 4 + 3) * MT + m] = v.w;
  }
}

// ---------------------------------------------------------------------------
// Kernel 0b: transpose LSTM input weights once.  Wt[k][n] (128x1024, 512KB);
// n<512 -> Wf[n][k], n>=512 -> Wb[n-512][k].
// ---------------------------------------------------------------------------
__global__ __launch_bounds__(256)
void transpose_w(const float* __restrict__ Wf, const float* __restrict__ Wb,
                 float* __restrict__ Wt)
{
  const int idx = blockIdx.x * 256 + threadIdx.x;  // over 128*1024
  const int k = idx >> 10, n = idx & 1023;
  Wt[idx] = (n < 512) ? Wf[n * E_ + k] : Wb[(n - 512) * E_ + k];
}

// ---------------------------------------------------------------------------
// Kernel 1: input projection GEMM.
// proj[b][tc][n] = sum_k Xt[k][m] * Wt[k][n] + (bih+bhh)[n']
//
// R11: 128(M) x 128(N) tile, 8x8 micro-tile, BK=32 double-buffered.
//   R8-R10 established the 64x64/4x4 structure is DS-READ-bound: 2
//   ds_read_b128 per 16 FMA -> 164us DS floor (measured ~190). 8x8 halves
//   DS per FMA -> ~84us floor. R4's spill avoided via float4 acc + direct
//   component FMAs (~125 VGPR); R5's latency exposure avoided via reg
//   prefetch of slice s+1 under slice s compute + double-buffered LDS.
//   Staging from k-major Xt/Wt is fully coalesced (512B runs per k-row).
// ---------------------------------------------------------------------------
#define MT8(L, R, A)                                                  \
  L.x += A * B0.x; L.y += A * B0.y; L.z += A * B0.z; L.w += A * B0.w; \
  R.x += A * B1.x; R.y += A * B1.y; R.z += A * B1.z; R.w += A * B1.w;

__global__ __launch_bounds__(256)
void proj_gemm(const float* __restrict__ Xt, const float* __restrict__ Wt,
               const float* __restrict__ bif, const float* __restrict__ bhf,
               const float* __restrict__ bib, const float* __restrict__ bhb,
               float* __restrict__ proj, int t0f, int Tc)
{
  __shared__ __align__(16) float Al[2][32][128];  // 32KB
  __shared__ __align__(16) float Bl[2][32][128];  // 32KB
  const int tid   = threadIdx.x;           // 0..255
  const int ntile = blockIdx.x;            // 0..7 (4 col-tiles per direction)
  const int mtile = blockIdx.y;            // 0..B*Tc/128-1
  const int dir   = ntile >> 2;
  const int n0    = (ntile & 3) << 7;      // within-dir col offset 0..384
  const int t0    = dir ? (T_ - t0f - Tc) : t0f;
  const int mrow0 = mtile * 128;           // chunk row base (within one b)
  const int b     = mrow0 / Tc;
  const size_t MT = (size_t)B_ * T_;
  const int mbase = b * T_ + t0 + (mrow0 - b * Tc);  // Xt col base (128 run)
  const int nbase = dir * 512 + n0;

  // staging map: float4 index f = tid + 256*j (j=0..3); kk=f>>5, quad=f&31.
  const int kk0 = tid >> 5;                // j=0 row
  const int mq0 = (tid & 31) * 4;

  float4 pa[4], pb[4];
  // ---- stage slice 0
#pragma unroll
  for (int j = 0; j < 4; ++j) {
    const int kk = kk0 + j * 8;            // (tid+256j)>>5 = kk0 + 8j
    pa[j] = *(const float4*)(Xt + (size_t)kk * MT + mbase + mq0);
    pb[j] = *(const float4*)(Wt + kk * 1024 + nbase + mq0);
  }
#pragma unroll
  for (int j = 0; j < 4; ++j) {
    const int kk = kk0 + j * 8;
    *(float4*)&Al[0][kk][mq0] = pa[j];
    *(float4*)&Bl[0][kk][mq0] = pb[j];
  }
  __syncthreads();

  const int mg = tid & 15, ng = tid >> 4;  // 16x16 thread grid
  float4 accL[8] = {}, accR[8] = {};       // rows mg*4+i / 64+mg*4+i
                                           // cols n0+ng*4.. / n0+64+ng*4..
  for (int s = 0; s < 4; ++s) {
    if (s < 3) {                           // prefetch slice s+1 into regs
      const int kb = (s + 1) * 32;
#pragma unroll
      for (int j = 0; j < 4; ++j) {
        const int kk = kb + kk0 + j * 8;
        pa[j] = *(const float4*)(Xt + (size_t)kk * MT + mbase + mq0);
        pb[j] = *(const float4*)(Wt + kk * 1024 + nbase + mq0);
      }
    }
    const int bs = s & 1;
#pragma unroll
    for (int k = 0; k < 32; ++k) {
      float4 A0 = *(const float4*)&Al[bs][k][mg * 4];
      float4 A1 = *(const float4*)&Al[bs][k][64 + mg * 4];
      float4 B0 = *(const float4*)&Bl[bs][k][ng * 4];
      float4 B1 = *(const float4*)&Bl[bs][k][64 + ng * 4];
      MT8(accL[0], accR[0], A0.x)
      MT8(accL[1], accR[1], A0.y)
      MT8(accL[2], accR[2], A0.z)
      MT8(accL[3], accR[3], A0.w)
      MT8(accL[4], accR[4], A1.x)
      MT8(accL[5], accR[5], A1.y)
      MT8(accL[6], accR[6], A1.z)
      MT8(accL[7], accR[7], A1.w)
    }
    if (s < 3) {
      __syncthreads();                     // readers of buf[bs^1] (s-1) done
      const int nb = bs ^ 1;
#pragma unroll
      for (int j = 0; j < 4; ++j) {
        const int kk = kk0 + j * 8;
        *(float4*)&Al[nb][kk][mq0] = pa[j];
        *(float4*)&Bl[nb][kk][mq0] = pb[j];
      }
      __syncthreads();                     // buf[nb] ready for slice s+1
    }
  }

  const float* bi = dir ? bib : bif;
  const float* bh = dir ? bhb : bhf;
  float4 biasL, biasR;
  biasL.x = bi[n0 + ng * 4 + 0] + bh[n0 + ng * 4 + 0];
  biasL.y = bi[n0 + ng * 4 + 1] + bh[n0 + ng * 4 + 1];
  biasL.z = bi[n0 + ng * 4 + 2] + bh[n0 + ng * 4 + 2];
  biasL.w = bi[n0 + ng * 4 + 3] + bh[n0 + ng * 4 + 3];
  biasR.x = bi[n0 + 64 + ng * 4 + 0] + bh[n0 + 64 + ng * 4 + 0];
  biasR.y = bi[n0 + 64 + ng * 4 + 1] + bh[n0 + 64 + ng * 4 + 1];
  biasR.z = bi[n0 + 64 + ng * 4 + 2] + bh[n0 + 64 + ng * 4 + 2];
  biasR.w = bi[n0 + 64 + ng * 4 + 3] + bh[n0 + 64 + ng * 4 + 3];
#pragma unroll
  for (int i = 0; i < 8; ++i) {
    const int mrow = mrow0 + (i >> 2) * 64 + mg * 4 + (i & 3);  // chunk row
    float* prow = proj + (size_t)mrow * 1024 + dir * G4 + n0;
    float4 oL, oR;
    oL.x = accL[i].x + biasL.x; oL.y = accL[i].y + biasL.y;
    oL.z = accL[i].z + biasL.z; oL.w = accL[i].w + biasL.w;
    oR.x = accR[i].x + biasR.x; oR.y = accR[i].y + biasR.y;
    oR.z = accR[i].z + biasR.z; oR.w = accR[i].w + biasR.w;
    *(float4*)&prow[ng * 4]      = oL;
    *(float4*)&prow[64 + ng * 4] = oR;
  }
}

// ---------------------------------------------------------------------------
// Fast, branchless nonlinearities (v_exp_f32 + v_rcp_f32).
// ---------------------------------------------------------------------------
__device__ __forceinline__ float fast_rcp(float x) {
  return __builtin_amdgcn_rcpf(x);
}
__device__ __forceinline__ float fast_sig(float x) {
  return fast_rcp(1.f + __expf(-x));
}
__device__ __forceinline__ float fast_tanh(float x) {
  return 2.f * fast_rcp(1.f + __expf(-2.f * x)) - 1.f;
}

// ---------------------------------------------------------------------------
// Kernel 2: LSTM recurrence (R7 structure + R8 fast gates — measured 206us,
// do not touch).  512 thr, 8 waves: unit u=wv*16+(l&15); gp=(l>>4)&1
// (0:i,f 1:g,o); kh=l>>5. 2 rows x 64 k per thread; k-halves via
// __shfl_xor(32); gate exchange via __shfl_xor(16); one barrier/step.
// Packed-sequence semantics: state frozen + output zeroed where t >= len.
// ---------------------------------------------------------------------------
__global__ __launch_bounds__(512, 2)
void lstm_chunk(const float* __restrict__ proj,
                const float* __restrict__ Whf, const float* __restrict__ Whb,
                const int* __restrict__ lengths,
                float* __restrict__ hs,
                float* __restrict__ sh, float* __restrict__ sc,
                int t0f, int Tc, int first)
{
  const int dir = blockIdx.x;
  const int b   = blockIdx.y;
  const int tid = threadIdx.x;
  const int l   = tid & 63;
  const int wv  = tid >> 6;
  const int u   = wv * 16 + (l & 15);      // hidden unit 0..127
  const int gp  = (l >> 4) & 1;            // 0: gates i,f   1: gates g,o
  const int kh  = l >> 5;                  // k half 0/1
  const int rowA = u + (gp ? 256 : 0);     // i or g
  const int rowB = rowA + 128;             // f or o
  const float* __restrict__ Whh = dir ? Whb : Whf;
  __shared__ __align__(16) float h_hist[2][H_];

  float wA[64], wB[64];
  {
    const float* wra = Whh + (size_t)rowA * H_ + kh * 64;
    const float* wrb = Whh + (size_t)rowB * H_ + kh * 64;
#pragma unroll
    for (int k = 0; k < 64; k += 4) {
      float4 va = *(const float4*)(wra + k);
      float4 vb = *(const float4*)(wrb + k);
      wA[k] = va.x; wA[k + 1] = va.y; wA[k + 2] = va.z; wA[k + 3] = va.w;
      wB[k] = vb.x; wB[k + 1] = vb.y; wB[k + 2] = vb.z; wB[k + 3] = vb.w;
    }
  }
#pragma unroll
  for (int k = 0; k < 64; ++k) {
    asm volatile("" : "+v"(wA[k]));
    asm volatile("" : "+v"(wB[k]));
  }

  const int len = lengths[b];
  const int t0  = dir ? (T_ - t0f - Tc) : t0f;
  const float fgp = (float)gp;
  const float kf  = 1.f + fgp;             // 1: sigmoid  2: tanh scaling
  float c = 0.f, h_reg = 0.f;
  if (!first) {
    c     = sc[(dir * B_ + b) * H_ + u];
    h_reg = sh[(dir * B_ + b) * H_ + u];
  }
  if (l < 16) h_hist[1][u] = h_reg;        // slot read by step 0
  __syncthreads();

  const float* projpA = proj + (size_t)b * Tc * 1024 + dir * G4 + rowA;
  const float* projpB = projpA + 128;
  const int tc00 = dir ? (Tc - 1) : 0;
  float pvA = projpA[(size_t)tc00 * 1024];
  float pvB = projpB[(size_t)tc00 * 1024];

  for (int s = 0; s < Tc; ++s) {
    const int tc = dir ? (Tc - 1 - s) : s;
    const int t  = t0 + tc;
    float nvA = 0.f, nvB = 0.f;
    if (s + 1 < Tc) {
      const int tcn = dir ? (Tc - 2 - s) : (s + 1);
      nvA = projpA[(size_t)tcn * 1024];
      nvB = projpB[(size_t)tcn * 1024];
    }
    const float* hp = h_hist[(s + 1) & 1] + kh * 64;   // h_{s-1}, own k-half
    float a0 = 0.f, a1 = 0.f, a2 = 0.f, a3 = 0.f;
#pragma unroll
    for (int k4 = 0; k4 < 16; ++k4) {
      float4 h4 = *(const float4*)&hp[k4 * 4];
      a0 += wA[4 * k4 + 0] * h4.x; a1 += wA[4 * k4 + 1] * h4.y;
      a0 += wA[4 * k4 + 2] * h4.z; a1 += wA[4 * k4 + 3] * h4.w;
      a2 += wB[4 * k4 + 0] * h4.x; a3 += wB[4 * k4 + 1] * h4.y;
      a2 += wB[4 * k4 + 2] * h4.z; a3 += wB[4 * k4 + 3] * h4.w;
    }
    float sA = a0 + a1; sA += __shfl_xor(sA, 32); sA += pvA;
    float sB = a2 + a3; sB += __shfl_xor(sB, 32); sB += pvB;
    // gA: sigmoid (gp=0) or tanh (gp=1), branchless; gB: always sigmoid.
    const float gA = kf * fast_rcp(1.f + __expf(-kf * sA)) - fgp;
    const float gB = fast_sig(sB);
    const float xA = __shfl_xor(gA, 16);
    const float xB = __shfl_xor(gB, 16);
    const float gi = gp ? xA : gA;
    const float gf = gp ? xB : gB;
    const float gg = gp ? gA : xA;
    const float go = gp ? gB : xB;
    const float cn = gf * c + gi * gg;
    const float hn = go * fast_tanh(cn);
    const bool  m  = (t < len);
    c     = m ? cn : c;
    h_reg = m ? hn : h_reg;
    if (l < 16) {
      h_hist[s & 1][u] = h_reg;
      hs[(size_t)(b * T_ + t) * 256 + dir * H_ + u] = m ? hn : 0.f;
    }
    __syncthreads();
    pvA = nvA; pvB = nvB;
  }
  if (l < 16 && wv == (u >> 4)) {          // one writer per unit
    sh[(dir * B_ + b) * H_ + u] = h_reg;
    sc[(dir * B_ + b) * H_ + u] = c;
  }
}

// ---------------------------------------------------------------------------
// Kernel 3: emissions em[m][k] = hs[m][:] . W_out[k][:] + b_out[k]
// ---------------------------------------------------------------------------
__global__ __launch_bounds__(256)
void emis_kernel(const float* __restrict__ hs, const float* __restrict__ Wout,
                 const float* __restrict__ bout, float* __restrict__ em)
{
  __shared__ __align__(16) float Wl[K_ * 256];
  const int tid = threadIdx.x;
  for (int i = tid; i < K_ * 256; i += 256) Wl[i] = Wout[i];
  __syncthreads();
  const int m = blockIdx.x * 256 + tid;
  const float* h = hs + (size_t)m * 256;
  float acc[K_] = {};
#pragma unroll 4
  for (int kk = 0; kk < 64; ++kk) {
    float4 h4 = *(const float4*)(h + kk * 4);
#pragma unroll
    for (int k9 = 0; k9 < K_; ++k9) {
      float4 w4 = *(const float4*)&Wl[k9 * 256 + kk * 4];
      acc[k9] += h4.x * w4.x + h4.y * w4.y + h4.z * w4.z + h4.w * w4.w;
    }
  }
#pragma unroll
  for (int k9 = 0; k9 < K_; ++k9) em[(size_t)m * K_ + k9] = acc[k9] + bout[k9];
}

// ---------------------------------------------------------------------------
// Kernel 4: Viterbi decode, one 64-lane wave per batch element.
// ---------------------------------------------------------------------------
__global__ __launch_bounds__(64)
void viterbi_kernel(const float* __restrict__ em, const int* __restrict__ lengths,
                    const float* __restrict__ st, const float* __restrict__ en,
                    const float* __restrict__ trans, int* __restrict__ tags)
{
  const int b    = blockIdx.x;
  const int lane = threadIdx.x;
  __shared__ unsigned char hist[(T_ - 1) * 16];
  const int len = lengths[b];
  float tr[K_];
#pragma unroll
  for (int j = 0; j < K_; ++j) tr[j] = (lane < K_) ? trans[j * K_ + lane] : 0.f;
  float s = (lane < K_) ? st[lane] + em[(size_t)(b * T_) * K_ + lane] : -1e30f;
  for (int t = 1; t < len; ++t) {
    float best = -1e30f; int bj = 0;
#pragma unroll
    for (int j = 0; j < K_; ++j) {
      float v = __shfl(s, j) + tr[j];
      if (v > best) { best = v; bj = j; }    // strict > == first-max (argmax)
    }
    if (lane < K_) {
      s = best + em[(size_t)(b * T_ + t) * K_ + lane];
      hist[(t - 1) * 16 + lane] = (unsigned char)bj;
    }
  }
  float fs = (lane < K_) ? s + en[lane] : -1e30f;
  float best = -1e30f; int last = 0;
#pragma unroll
  for (int j = 0; j < K_; ++j) {
    float v = __shfl(fs, j);
    if (v > best) { best = v; last = j; }
  }
  __syncthreads();                            // hist visible to lane 0
  if (lane == 0) {
    int tag = last;
    tags[b * T_ + len - 1] = tag;
    for (int t = len - 2; t >= 0; --t) {
      tag = hist[t * 16 + tag];
      tags[b * T_ + t] = tag;
    }
  }
  for (int t = len + lane; t < T_; t += 64) tags[b * T_ + t] = 0;
}

// ---------------------------------------------------------------------------
extern "C" void kernel_launch(void* const* d_in, const int* in_sizes, int n_in,
                              void* d_out, int out_size, void* d_ws, size_t ws_size,
                              hipStream_t stream)
{
  const int*   sent  = (const int*)d_in[0];
  const int*   lens  = (const int*)d_in[1];
  const float* embed = (const float*)d_in[2];
  const float* Wif   = (const float*)d_in[3];
  const float* Whf   = (const float*)d_in[4];
  const float* bif   = (const float*)d_in[5];
  const float* bhf   = (const float*)d_in[6];
  const float* Wib   = (const float*)d_in[7];
  const float* Whb   = (const float*)d_in[8];
  const float* bib   = (const float*)d_in[9];
  const float* bhb   = (const float*)d_in[10];
  const float* Wout  = (const float*)d_in[11];
  const float* bout  = (const float*)d_in[12];
  const float* stt   = (const float*)d_in[13];
  const float* ent   = (const float*)d_in[14];
  const float* trans = (const float*)d_in[15];
  int* tags = (int*)d_out;

  // workspace layout (floats): hs | em | sh | sc | Xt | Wt | proj(chunked)
  float* ws   = (float*)d_ws;
  float* hs   = ws;                                  // B*T*256   (67.1 MB)
  float* em   = hs + (size_t)B_ * T_ * 256;          // B*T*9     ( 2.4 MB)
  float* sh   = em + (size_t)B_ * T_ * K_;           // 2*B*H carry h
  float* sc   = sh + (size_t)2 * B_ * H_;            // 2*B*H carry c
  float* Xt   = sc + (size_t)2 * B_ * H_;            // 128*B*T   (33.6 MB)
  float* Wt   = Xt + (size_t)E_ * B_ * T_;           // 128*1024  ( 0.5 MB)
  float* proj = Wt + (size_t)E_ * 1024;
  const size_t fixed_bytes = (size_t)(proj - ws) * sizeof(float);

  // largest time-chunk whose proj buffer fits (floor 128: GEMM M-tile = 128)
  int Tc = 512;
  while (Tc > 128 && fixed_bytes + (size_t)B_ * Tc * 1024 * sizeof(float) > ws_size)
    Tc >>= 1;

  // one-time operand preparation
  hipLaunchKernelGGL(gather_x, dim3((B_ * T_) / 256), dim3(256), 0, stream,
                     sent, embed, Xt);
  hipLaunchKernelGGL(transpose_w, dim3((E_ * 1024) / 256), dim3(256), 0, stream,
                     Wif, Wib, Wt);

  const int nch = T_ / Tc;
  for (int c2 = 0; c2 < nch; ++c2) {
    const int t0f = c2 * Tc;
    dim3 g1(8, (B_ * Tc) >> 7);
    hipLaunchKernelGGL(proj_gemm, g1, dim3(256), 0, stream,
                       Xt, Wt, bif, bhf, bib, bhb, proj, t0f, Tc);
    dim3 g2(2, B_);
    hipLaunchKernelGGL(lstm_chunk, g2, dim3(512), 0, stream,
                       proj, Whf, Whb, lens, hs, sh, sc, t0f, Tc, (int)(c2 == 0));
  }
  hipLaunchKernelGGL(emis_kernel, dim3((B_ * T_) / 256), dim3(256), 0, stream,
                     hs, Wout, bout, em);
  hipLaunchKernelGGL(viterbi_kernel, dim3(B_), dim3(64), 0, stream,
                     em, lens, stt, ent, trans, tags);
}

// Round 12
// 918.446 us; speedup vs baseline: 1.6719x; 1.6719x over previous
//
#include <hip/hip_runtime.h>
#include <cmath>

#define B_  128
#define T_  512
#define E_  128
#define H_  128
#define G4  512   // 4*H
#define K_  9

// ---------------------------------------------------------------------------
// Kernel 0a: gather + transpose embeddings once per launch.
//   Xt[k][b*T+t] = embed[sent[b][t]][k]   (33.6 MB, fp32 exact)
// ---------------------------------------------------------------------------
__global__ __launch_bounds__(256)
void gather_x(const int* __restrict__ sent, const float* __restrict__ embed,
              float* __restrict__ Xt)
{
  const int m = blockIdx.x * 256 + threadIdx.x;   // 0 .. B*T-1  (b*T+t)
  const int vid = sent[m];
  const float* er = embed + (size_t)vid * E_;
  const size_t MT = (size_t)B_ * T_;
#pragma unroll
  for (int q = 0; q < 32; ++q) {
    float4 v = *(const float4*)(er + q * 4);      // gather read (once)
    Xt[(size_t)(q * 4 + 0) * MT + m] = v.x;       // coalesced writes
    Xt[(size_t)(q * 4 + 1) * MT + m] = v.y;
    Xt[(size_t)(q * 4 + 2) * MT + m] = v.z;
    Xt[(size_t)(q * 4 + 3) * MT + m] = v.w;
  }
}

// ---------------------------------------------------------------------------
// Kernel 0b: transpose LSTM input weights once.  Wt[k][n] (128x1024, 512KB);
// n<512 -> Wf[n][k], n>=512 -> Wb[n-512][k].
// ---------------------------------------------------------------------------
__global__ __launch_bounds__(256)
void transpose_w(const float* __restrict__ Wf, const float* __restrict__ Wb,
                 float* __restrict__ Wt)
{
  const int idx = blockIdx.x * 256 + threadIdx.x;  // over 128*1024
  const int k = idx >> 10, n = idx & 1023;
  Wt[idx] = (n < 512) ? Wf[n * E_ + k] : Wb[(n - 512) * E_ + k];
}

// ---------------------------------------------------------------------------
// Kernel 1: input projection GEMM.
// proj[b][tc][n] = sum_k Xt[k][m] * Wt[k][n] + (bih+bhh)[n']
//
// R12: A-only LDS; B read straight from global (L1-resident).
//   R8-R11 established: the 4x4 structure is DS-read-bound (2 ds_read_b128
//   per 16 FMA = 164us DS floor), and every 8x8 variant spills (R4/R11:
//   VGPR=256 + scratch thrash). This keeps the proven 4x4 register
//   footprint but removes HALF the DS traffic: B's per-wave working set is
//   4 float4 per k (8KB over all k) -> L1-resident broadcast load, so only
//   A is staged in LDS (32KB -> 4 blocks/CU, 16 waves to hide L1 latency).
//   Per thread per k: 1 ds_read_b128 + 1 L1 global float4 + 16 FMA.
//   New floors: DS ~82us, VALU ~55us, B-traffic ~0.3GB (noise).
// ---------------------------------------------------------------------------
__global__ __launch_bounds__(256, 4)
void proj_gemm(const float* __restrict__ Xt, const float* __restrict__ Wt,
               const float* __restrict__ bif, const float* __restrict__ bhf,
               const float* __restrict__ bib, const float* __restrict__ bhb,
               float* __restrict__ proj, int t0f, int Tc)
{
  __shared__ __align__(16) float Al[128][64];   // [k][m] 32KB
  const int tid   = threadIdx.x;
  const int ntile = blockIdx.x;            // 0..15
  const int mtile = blockIdx.y;
  const int tpb   = Tc >> 6;               // 64-row tiles per batch element
  const int b     = mtile / tpb;
  const int toff  = (mtile - b * tpb) << 6;
  const int dir   = ntile >> 3;
  const int t0    = dir ? (T_ - t0f - Tc) : t0f;
  const int n0    = (ntile & 7) << 6;      // col offset within direction
  const size_t MT = (size_t)B_ * T_;
  const int mbase = b * T_ + t0 + toff;    // Xt col base (64-long run)
  const int nbase = dir * 512 + n0;

  // ---- stage A, k-major, coalesced from Xt (8 float4 per thread)
  {
    const int kk0 = tid >> 4;              // 0..15, +16 per j
    const int q4  = (tid & 15) * 4;        // m-quad
#pragma unroll
    for (int j = 0; j < 8; ++j) {
      const int kk = kk0 + j * 16;
      *(float4*)&Al[kk][q4] = *(const float4*)(Xt + (size_t)kk * MT + mbase + q4);
    }
  }
  __syncthreads();

  const int mg = tid & 15, ng = tid >> 4;
  const float* __restrict__ bp = Wt + nbase + ng * 4;  // +1024 per k
  float acc[4][4] = {};
#pragma unroll 8
  for (int k = 0; k < 128; ++k) {
    float4 a  = *(const float4*)&Al[k][mg * 4];        // LDS broadcast
    float4 bb = *(const float4*)(bp + k * 1024);       // L1-resident global
    acc[0][0] += a.x * bb.x; acc[0][1] += a.x * bb.y; acc[0][2] += a.x * bb.z; acc[0][3] += a.x * bb.w;
    acc[1][0] += a.y * bb.x; acc[1][1] += a.y * bb.y; acc[1][2] += a.y * bb.z; acc[1][3] += a.y * bb.w;
    acc[2][0] += a.z * bb.x; acc[2][1] += a.z * bb.y; acc[2][2] += a.z * bb.z; acc[2][3] += a.z * bb.w;
    acc[3][0] += a.w * bb.x; acc[3][1] += a.w * bb.y; acc[3][2] += a.w * bb.z; acc[3][3] += a.w * bb.w;
  }

  const float* bi = dir ? bib : bif;
  const float* bh = dir ? bhb : bhf;
  const int nl = ng * 4;
  float4 bias;
  bias.x = bi[n0 + nl + 0] + bh[n0 + nl + 0];
  bias.y = bi[n0 + nl + 1] + bh[n0 + nl + 1];
  bias.z = bi[n0 + nl + 2] + bh[n0 + nl + 2];
  bias.w = bi[n0 + nl + 3] + bh[n0 + nl + 3];
#pragma unroll
  for (int i = 0; i < 4; ++i) {
    const int tloc = toff + mg * 4 + i;
    float4 o;
    o.x = acc[i][0] + bias.x; o.y = acc[i][1] + bias.y;
    o.z = acc[i][2] + bias.z; o.w = acc[i][3] + bias.w;
    *(float4*)&proj[((size_t)(b * Tc + tloc)) * 1024 + dir * G4 + n0 + nl] = o;
  }
}

// ---------------------------------------------------------------------------
// Fast, branchless nonlinearities (v_exp_f32 + v_rcp_f32).
// ---------------------------------------------------------------------------
__device__ __forceinline__ float fast_rcp(float x) {
  return __builtin_amdgcn_rcpf(x);
}
__device__ __forceinline__ float fast_sig(float x) {
  return fast_rcp(1.f + __expf(-x));
}
__device__ __forceinline__ float fast_tanh(float x) {
  return 2.f * fast_rcp(1.f + __expf(-2.f * x)) - 1.f;
}

// ---------------------------------------------------------------------------
// Kernel 2: LSTM recurrence (R7 structure + R8 fast gates — measured 206us,
// do not touch).  512 thr, 8 waves: unit u=wv*16+(l&15); gp=(l>>4)&1
// (0:i,f 1:g,o); kh=l>>5. 2 rows x 64 k per thread; k-halves via
// __shfl_xor(32); gate exchange via __shfl_xor(16); one barrier/step.
// Packed-sequence semantics: state frozen + output zeroed where t >= len.
// ---------------------------------------------------------------------------
__global__ __launch_bounds__(512, 2)
void lstm_chunk(const float* __restrict__ proj,
                const float* __restrict__ Whf, const float* __restrict__ Whb,
                const int* __restrict__ lengths,
                float* __restrict__ hs,
                float* __restrict__ sh, float* __restrict__ sc,
                int t0f, int Tc, int first)
{
  const int dir = blockIdx.x;
  const int b   = blockIdx.y;
  const int tid = threadIdx.x;
  const int l   = tid & 63;
  const int wv  = tid >> 6;
  const int u   = wv * 16 + (l & 15);      // hidden unit 0..127
  const int gp  = (l >> 4) & 1;            // 0: gates i,f   1: gates g,o
  const int kh  = l >> 5;                  // k half 0/1
  const int rowA = u + (gp ? 256 : 0);     // i or g
  const int rowB = rowA + 128;             // f or o
  const float* __restrict__ Whh = dir ? Whb : Whf;
  __shared__ __align__(16) float h_hist[2][H_];

  float wA[64], wB[64];
  {
    const float* wra = Whh + (size_t)rowA * H_ + kh * 64;
    const float* wrb = Whh + (size_t)rowB * H_ + kh * 64;
#pragma unroll
    for (int k = 0; k < 64; k += 4) {
      float4 va = *(const float4*)(wra + k);
      float4 vb = *(const float4*)(wrb + k);
      wA[k] = va.x; wA[k + 1] = va.y; wA[k + 2] = va.z; wA[k + 3] = va.w;
      wB[k] = vb.x; wB[k + 1] = vb.y; wB[k + 2] = vb.z; wB[k + 3] = vb.w;
    }
  }
#pragma unroll
  for (int k = 0; k < 64; ++k) {
    asm volatile("" : "+v"(wA[k]));
    asm volatile("" : "+v"(wB[k]));
  }

  const int len = lengths[b];
  const int t0  = dir ? (T_ - t0f - Tc) : t0f;
  const float fgp = (float)gp;
  const float kf  = 1.f + fgp;             // 1: sigmoid  2: tanh scaling
  float c = 0.f, h_reg = 0.f;
  if (!first) {
    c     = sc[(dir * B_ + b) * H_ + u];
    h_reg = sh[(dir * B_ + b) * H_ + u];
  }
  if (l < 16) h_hist[1][u] = h_reg;        // slot read by step 0
  __syncthreads();

  const float* projpA = proj + (size_t)b * Tc * 1024 + dir * G4 + rowA;
  const float* projpB = projpA + 128;
  const int tc00 = dir ? (Tc - 1) : 0;
  float pvA = projpA[(size_t)tc00 * 1024];
  float pvB = projpB[(size_t)tc00 * 1024];

  for (int s = 0; s < Tc; ++s) {
    const int tc = dir ? (Tc - 1 - s) : s;
    const int t  = t0 + tc;
    float nvA = 0.f, nvB = 0.f;
    if (s + 1 < Tc) {
      const int tcn = dir ? (Tc - 2 - s) : (s + 1);
      nvA = projpA[(size_t)tcn * 1024];
      nvB = projpB[(size_t)tcn * 1024];
    }
    const float* hp = h_hist[(s + 1) & 1] + kh * 64;   // h_{s-1}, own k-half
    float a0 = 0.f, a1 = 0.f, a2 = 0.f, a3 = 0.f;
#pragma unroll
    for (int k4 = 0; k4 < 16; ++k4) {
      float4 h4 = *(const float4*)&hp[k4 * 4];
      a0 += wA[4 * k4 + 0] * h4.x; a1 += wA[4 * k4 + 1] * h4.y;
      a0 += wA[4 * k4 + 2] * h4.z; a1 += wA[4 * k4 + 3] * h4.w;
      a2 += wB[4 * k4 + 0] * h4.x; a3 += wB[4 * k4 + 1] * h4.y;
      a2 += wB[4 * k4 + 2] * h4.z; a3 += wB[4 * k4 + 3] * h4.w;
    }
    float sA = a0 + a1; sA += __shfl_xor(sA, 32); sA += pvA;
    float sB = a2 + a3; sB += __shfl_xor(sB, 32); sB += pvB;
    // gA: sigmoid (gp=0) or tanh (gp=1), branchless; gB: always sigmoid.
    const float gA = kf * fast_rcp(1.f + __expf(-kf * sA)) - fgp;
    const float gB = fast_sig(sB);
    const float xA = __shfl_xor(gA, 16);
    const float xB = __shfl_xor(gB, 16);
    const float gi = gp ? xA : gA;
    const float gf = gp ? xB : gB;
    const float gg = gp ? gA : xA;
    const float go = gp ? gB : xB;
    const float cn = gf * c + gi * gg;
    const float hn = go * fast_tanh(cn);
    const bool  m  = (t < len);
    c     = m ? cn : c;
    h_reg = m ? hn : h_reg;
    if (l < 16) {
      h_hist[s & 1][u] = h_reg;
      hs[(size_t)(b * T_ + t) * 256 + dir * H_ + u] = m ? hn : 0.f;
    }
    __syncthreads();
    pvA = nvA; pvB = nvB;
  }
  if (l < 16 && wv == (u >> 4)) {          // one writer per unit
    sh[(dir * B_ + b) * H_ + u] = h_reg;
    sc[(dir * B_ + b) * H_ + u] = c;
  }
}

// ---------------------------------------------------------------------------
// Kernel 3: emissions em[m][k] = hs[m][:] . W_out[k][:] + b_out[k]
// ---------------------------------------------------------------------------
__global__ __launch_bounds__(256)
void emis_kernel(const float* __restrict__ hs, const float* __restrict__ Wout,
                 const float* __restrict__ bout, float* __restrict__ em)
{
  __shared__ __align__(16) float Wl[K_ * 256];
  const int tid = threadIdx.x;
  for (int i = tid; i < K_ * 256; i += 256) Wl[i] = Wout[i];
  __syncthreads();
  const int m = blockIdx.x * 256 + tid;
  const float* h = hs + (size_t)m * 256;
  float acc[K_] = {};
#pragma unroll 4
  for (int kk = 0; kk < 64; ++kk) {
    float4 h4 = *(const float4*)(h + kk * 4);
#pragma unroll
    for (int k9 = 0; k9 < K_; ++k9) {
      float4 w4 = *(const float4*)&Wl[k9 * 256 + kk * 4];
      acc[k9] += h4.x * w4.x + h4.y * w4.y + h4.z * w4.z + h4.w * w4.w;
    }
  }
#pragma unroll
  for (int k9 = 0; k9 < K_; ++k9) em[(size_t)m * K_ + k9] = acc[k9] + bout[k9];
}

// ---------------------------------------------------------------------------
// Kernel 4: Viterbi decode, one 64-lane wave per batch element.
// ---------------------------------------------------------------------------
__global__ __launch_bounds__(64)
void viterbi_kernel(const float* __restrict__ em, const int* __restrict__ lengths,
                    const float* __restrict__ st, const float* __restrict__ en,
                    const float* __restrict__ trans, int* __restrict__ tags)
{
  const int b    = blockIdx.x;
  const int lane = threadIdx.x;
  __shared__ unsigned char hist[(T_ - 1) * 16];
  const int len = lengths[b];
  float tr[K_];
#pragma unroll
  for (int j = 0; j < K_; ++j) tr[j] = (lane < K_) ? trans[j * K_ + lane] : 0.f;
  float s = (lane < K_) ? st[lane] + em[(size_t)(b * T_) * K_ + lane] : -1e30f;
  for (int t = 1; t < len; ++t) {
    float best = -1e30f; int bj = 0;
#pragma unroll
    for (int j = 0; j < K_; ++j) {
      float v = __shfl(s, j) + tr[j];
      if (v > best) { best = v; bj = j; }    // strict > == first-max (argmax)
    }
    if (lane < K_) {
      s = best + em[(size_t)(b * T_ + t) * K_ + lane];
      hist[(t - 1) * 16 + lane] = (unsigned char)bj;
    }
  }
  float fs = (lane < K_) ? s + en[lane] : -1e30f;
  float best = -1e30f; int last = 0;
#pragma unroll
  for (int j = 0; j < K_; ++j) {
    float v = __shfl(fs, j);
    if (v > best) { best = v; last = j; }
  }
  __syncthreads();                            // hist visible to lane 0
  if (lane == 0) {
    int tag = last;
    tags[b * T_ + len - 1] = tag;
    for (int t = len - 2; t >= 0; --t) {
      tag = hist[t * 16 + tag];
      tags[b * T_ + t] = tag;
    }
  }
  for (int t = len + lane; t < T_; t += 64) tags[b * T_ + t] = 0;
}

// ---------------------------------------------------------------------------
extern "C" void kernel_launch(void* const* d_in, const int* in_sizes, int n_in,
                              void* d_out, int out_size, void* d_ws, size_t ws_size,
                              hipStream_t stream)
{
  const int*   sent  = (const int*)d_in[0];
  const int*   lens  = (const int*)d_in[1];
  const float* embed = (const float*)d_in[2];
  const float* Wif   = (const float*)d_in[3];
  const float* Whf   = (const float*)d_in[4];
  const float* bif   = (const float*)d_in[5];
  const float* bhf   = (const float*)d_in[6];
  const float* Wib   = (const float*)d_in[7];
  const float* Whb   = (const float*)d_in[8];
  const float* bib   = (const float*)d_in[9];
  const float* bhb   = (const float*)d_in[10];
  const float* Wout  = (const float*)d_in[11];
  const float* bout  = (const float*)d_in[12];
  const float* stt   = (const float*)d_in[13];
  const float* ent   = (const float*)d_in[14];
  const float* trans = (const float*)d_in[15];
  int* tags = (int*)d_out;

  // workspace layout (floats): hs | em | sh | sc | Xt | Wt | proj(chunked)
  float* ws   = (float*)d_ws;
  float* hs   = ws;                                  // B*T*256   (67.1 MB)
  float* em   = hs + (size_t)B_ * T_ * 256;          // B*T*9     ( 2.4 MB)
  float* sh   = em + (size_t)B_ * T_ * K_;           // 2*B*H carry h
  float* sc   = sh + (size_t)2 * B_ * H_;            // 2*B*H carry c
  float* Xt   = sc + (size_t)2 * B_ * H_;            // 128*B*T   (33.6 MB)
  float* Wt   = Xt + (size_t)E_ * B_ * T_;           // 128*1024  ( 0.5 MB)
  float* proj = Wt + (size_t)E_ * 1024;
  const size_t fixed_bytes = (size_t)(proj - ws) * sizeof(float);

  // largest time-chunk whose proj buffer fits the workspace (floor at 64)
  int Tc = 512;
  while (Tc > 64 && fixed_bytes + (size_t)B_ * Tc * 1024 * sizeof(float) > ws_size)
    Tc >>= 1;

  // one-time operand preparation
  hipLaunchKernelGGL(gather_x, dim3((B_ * T_) / 256), dim3(256), 0, stream,
                     sent, embed, Xt);
  hipLaunchKernelGGL(transpose_w, dim3((E_ * 1024) / 256), dim3(256), 0, stream,
                     Wif, Wib, Wt);

  const int nch = T_ / Tc;
  for (int c2 = 0; c2 < nch; ++c2) {
    const int t0f = c2 * Tc;
    dim3 g1(16, B_ * (Tc >> 6));
    hipLaunchKernelGGL(proj_gemm, g1, dim3(256), 0, stream,
                       Xt, Wt, bif, bhf, bib, bhb, proj, t0f, Tc);
    dim3 g2(2, B_);
    hipLaunchKernelGGL(lstm_chunk, g2, dim3(512), 0, stream,
                       proj, Whf, Whb, lens, hs, sh, sc, t0f, Tc, (int)(c2 == 0));
  }
  hipLaunchKernelGGL(emis_kernel, dim3((B_ * T_) / 256), dim3(256), 0, stream,
                     hs, Wout, bout, em);
  hipLaunchKernelGGL(viterbi_kernel, dim3(B_), dim3(64), 0, stream,
                     em, lens, stt, ent, trans, tags);
}